// Round 10
// baseline (933.246 us; speedup 1.0000x reference)
//
#include <hip/hip_runtime.h>

#define N_NODES 25000   // = 3125 * 8 exactly
#define E_EDGES 400000
#define KM 200     // message channels
#define RS 224     // fused row stride (floats): 200 A/B + 20 x + pad (896 B)

// ---------------- sort-by-dst (CSR build) ----------------

__global__ void hist_kernel(const int* __restrict__ edges, int* __restrict__ hist) {
  int e = blockIdx.x * blockDim.x + threadIdx.x;
  if (e < E_EDGES) atomicAdd(&hist[edges[E_EDGES + e]], 1);
}

__global__ void scan_kernel(const int* __restrict__ hist, int* __restrict__ off,
                            int* __restrict__ cursor) {
  __shared__ int sums[1024];
  const int CH = (N_NODES + 1023) / 1024;  // 25
  int tid = threadIdx.x;
  int base = tid * CH;
  int s = 0;
  for (int i = 0; i < CH; i++) {
    int idx = base + i;
    if (idx < N_NODES) s += hist[idx];
  }
  sums[tid] = s;
  __syncthreads();
  for (int d = 1; d < 1024; d <<= 1) {
    int v = (tid >= d) ? sums[tid - d] : 0;
    __syncthreads();
    sums[tid] += v;
    __syncthreads();
  }
  int run = (tid == 0) ? 0 : sums[tid - 1];
  for (int i = 0; i < CH; i++) {
    int idx = base + i;
    if (idx < N_NODES) {
      off[idx] = run;
      cursor[idx] = run;
      run += hist[idx];
    }
  }
  if (tid == 1023) off[N_NODES] = run;  // == E
}

__global__ void scatter_kernel(const int* __restrict__ edges, int* __restrict__ cursor,
                               int* __restrict__ srcS, int* __restrict__ dstS) {
  int e = blockIdx.x * blockDim.x + threadIdx.x;
  if (e < E_EDGES) {
    int s = edges[e];
    int d = edges[E_EDGES + e];
    int pos = atomicAdd(&cursor[d], 1);
    srcS[pos] = s;
    dstS[pos] = d;
  }
}

// ---------------- per-layer kernels ----------------

// Node prep (layer d only): xv = xin (no relu, CIN=1)
//   A2[n] = [ xv@Wm1_top + bm1 (200) | xv (1) | pad ]
//   B2[n] = [ xv@Wm1_bot       (200) | xv (1) | pad ]
__global__ void prep_d_kernel(const float* __restrict__ xin,
                              const float* __restrict__ Wm1, const float* __restrict__ bm1,
                              float* __restrict__ A2, float* __restrict__ B2,
                              float* __restrict__ xr) {
  const int NT = 8;
  int k = threadIdx.x;  // 0..255
  float wa = 0.f, wb = 0.f, bm = 0.f;
  if (k < KM) {
    bm = bm1[k];
    wa = Wm1[k];
    wb = Wm1[KM + k];
  }
  int n0 = blockIdx.x * NT;
  for (int i = 0; i < NT; i++) {
    int n = n0 + i;
    float xv = xin[n];
    size_t row = (size_t)n * RS;
    if (k == 0) {
      xr[n] = xv;
      A2[row + KM] = xv;
      B2[row + KM] = xv;
    }
    if (k < KM) {
      A2[row + k] = bm + xv * wa;
      B2[row + k] = xv * wb;
    }
  }
}

// Edge kernel: one thread per (dst-sorted) edge.
// h_k = relu(A2[dst][k] + B2[src][k]); gate = h@Wm2 + bm2;
// gd layout [c][e]: coalesced nontemporal dword stores.
template <int CIN>
__global__ void __launch_bounds__(256) edge_kernel(
    const int* __restrict__ srcS, const int* __restrict__ dstS,
    const float* __restrict__ A2, const float* __restrict__ B2,
    const float* __restrict__ Wm2, const float* __restrict__ bm2,
    float* __restrict__ gd) {
  int e = blockIdx.x * 256 + threadIdx.x;
  if (e >= E_EDGES) return;
  int src = srcS[e];
  int dst = dstS[e];
  const float* Ar = A2 + (size_t)dst * RS;
  const float* Br = B2 + (size_t)src * RS;
  float gate[CIN];
#pragma unroll
  for (int c = 0; c < CIN; c++) gate[c] = bm2[c];
#pragma unroll 4
  for (int k = 0; k < KM; k += 4) {
    float4 a4 = *(const float4*)(Ar + k);
    float4 b4 = *(const float4*)(Br + k);
    float h0 = fmaxf(a4.x + b4.x, 0.f);
    float h1 = fmaxf(a4.y + b4.y, 0.f);
    float h2 = fmaxf(a4.z + b4.z, 0.f);
    float h3 = fmaxf(a4.w + b4.w, 0.f);
#pragma unroll
    for (int c = 0; c < CIN; c++) {
      gate[c] += h0 * Wm2[(k + 0) * CIN + c] + h1 * Wm2[(k + 1) * CIN + c] +
                 h2 * Wm2[(k + 2) * CIN + c] + h3 * Wm2[(k + 3) * CIN + c];
    }
  }
  // x-diff tails (same rows, L1-hot) + coalesced nontemporal stores
  if constexpr (CIN % 4 == 0) {
#pragma unroll
    for (int q = 0; q < CIN / 4; q++) {
      float4 xa = *(const float4*)(Ar + KM + 4 * q);
      float4 xb = *(const float4*)(Br + KM + 4 * q);
      float xd[4] = {xa.x - xb.x, xa.y - xb.y, xa.z - xb.z, xa.w - xb.w};
#pragma unroll
      for (int j = 0; j < 4; j++) {
        int c = 4 * q + j;
        __builtin_nontemporal_store(gate[c] * xd[j], gd + (size_t)c * E_EDGES + e);
      }
    }
  } else {
#pragma unroll
    for (int c = 0; c < CIN; c++) {
      __builtin_nontemporal_store(gate[c] * (Ar[KM + c] - Br[KM + c]),
                                  gd + (size_t)c * E_EDGES + e);
    }
  }
}

// afp1: after layer-d edge (gd 1-channel). Per block: 8 nodes.
//  phase1: agg; phase2: fin(1->20)+relu -> xv + xr_next; phase3: prep (20->200).
__global__ void __launch_bounds__(256) afp1_kernel(
    const float* __restrict__ gd, const int* __restrict__ off,
    const float* __restrict__ xrp,
    const float* __restrict__ W1, const float* __restrict__ b1,
    const float* __restrict__ W2, const float* __restrict__ b2,
    const float* __restrict__ Wm1n, const float* __restrict__ bm1n,
    float* __restrict__ A2, float* __restrict__ B2, float* __restrict__ xrn) {
  __shared__ float ag[8], xp[8], degs[8];
  __shared__ float xv[8][21];
  int tid = threadIdx.x;
  int n0 = blockIdx.x * 8;
  if (tid < 8) {
    int n = n0 + tid;
    int s = off[n], t = off[n + 1];
    float v = 0.f;
    for (int e = s; e < t; e++) v += gd[e];
    ag[tid] = v;
    xp[tid] = xrp[n];
    degs[tid] = (float)(t - s);
  }
  __syncthreads();
  if (tid < 160) {
    int o = tid >> 3, nl = tid & 7;
    float v = b1[o] + degs[nl] * b2[o] + ag[nl] * W2[o] + xp[nl] * W1[o];
    float r = fmaxf(v, 0.f);
    xv[nl][o] = r;
    xrn[(n0 + nl) * 20 + o] = r;
  }
  __syncthreads();
  int k = tid;
  if (k < KM) {
    float wa[20], wb[20];
    float bm = bm1n[k];
#pragma unroll
    for (int c = 0; c < 20; c++) {
      wa[c] = Wm1n[c * KM + k];
      wb[c] = Wm1n[(20 + c) * KM + k];
    }
    for (int nl = 0; nl < 8; nl++) {
      float a = bm, b = 0.f;
#pragma unroll
      for (int c = 0; c < 20; c++) {
        a += xv[nl][c] * wa[c];
        b += xv[nl][c] * wb[c];
      }
      size_t row = (size_t)(n0 + nl) * RS;
      A2[row + k] = a;
      B2[row + k] = b;
      if (k < 20) {
        A2[row + KM + k] = xv[nl][k];
        B2[row + KM + k] = xv[nl][k];
      }
    }
  }
}

// afp20: after a hidden edge (gd 20-channel). Same 3 phases, CIN=20.
__global__ void __launch_bounds__(256) afp20_kernel(
    const float* __restrict__ gd, const int* __restrict__ off,
    const float* __restrict__ xrp,
    const float* __restrict__ W1, const float* __restrict__ b1,
    const float* __restrict__ W2, const float* __restrict__ b2,
    const float* __restrict__ Wm1n, const float* __restrict__ bm1n,
    float* __restrict__ A2, float* __restrict__ B2, float* __restrict__ xrn) {
  __shared__ float ag[8][21], xp[8][21], xv[8][21], degs[8];
  int tid = threadIdx.x;
  int n0 = blockIdx.x * 8;
  if (tid < 160) {
    int c = tid >> 3, nl = tid & 7;  // adjacent lanes: same c, adjacent n
    int n = n0 + nl;
    int s = off[n], t = off[n + 1];
    const float* g = gd + (size_t)c * E_EDGES;
    float v = 0.f;
    for (int e = s; e < t; e++) v += g[e];
    ag[nl][c] = v;
    xp[nl][c] = xrp[n * 20 + c];
    if (c == 0) degs[nl] = (float)(t - s);
  }
  __syncthreads();
  if (tid < 160) {
    int o = tid >> 3, nl = tid & 7;
    float v = b1[o] + degs[nl] * b2[o];
#pragma unroll
    for (int c = 0; c < 20; c++) {
      v += ag[nl][c] * W2[c * 20 + o] + xp[nl][c] * W1[c * 20 + o];
    }
    float r = fmaxf(v, 0.f);
    xv[nl][o] = r;
    xrn[(n0 + nl) * 20 + o] = r;
  }
  __syncthreads();
  int k = tid;
  if (k < KM) {
    float wa[20], wb[20];
    float bm = bm1n[k];
#pragma unroll
    for (int c = 0; c < 20; c++) {
      wa[c] = Wm1n[c * KM + k];
      wb[c] = Wm1n[(20 + c) * KM + k];
    }
    for (int nl = 0; nl < 8; nl++) {
      float a = bm, b = 0.f;
#pragma unroll
      for (int c = 0; c < 20; c++) {
        a += xv[nl][c] * wa[c];
        b += xv[nl][c] * wb[c];
      }
      size_t row = (size_t)(n0 + nl) * RS;
      A2[row + k] = a;
      B2[row + k] = b;
      if (k < 20) {
        A2[row + KM + k] = xv[nl][k];
        B2[row + KM + k] = xv[nl][k];
      }
    }
  }
}

// final: agg(20ch) + fin(20->1), no relu, writes d_out.
__global__ void __launch_bounds__(256) aggfin_out_kernel(
    const float* __restrict__ gd, const int* __restrict__ off,
    const float* __restrict__ xrp,
    const float* __restrict__ W1, const float* __restrict__ b1,
    const float* __restrict__ W2, const float* __restrict__ b2,
    float* __restrict__ out) {
  __shared__ float ag[8][21], xp[8][21], degs[8];
  int tid = threadIdx.x;
  int n0 = blockIdx.x * 8;
  if (tid < 160) {
    int c = tid >> 3, nl = tid & 7;
    int n = n0 + nl;
    int s = off[n], t = off[n + 1];
    const float* g = gd + (size_t)c * E_EDGES;
    float v = 0.f;
    for (int e = s; e < t; e++) v += g[e];
    ag[nl][c] = v;
    xp[nl][c] = xrp[n * 20 + c];
    if (c == 0) degs[nl] = (float)(t - s);
  }
  __syncthreads();
  if (tid < 8) {
    float v = b1[0] + degs[tid] * b2[0];
#pragma unroll
    for (int c = 0; c < 20; c++) {
      v += ag[tid][c] * W2[c] + xp[tid][c] * W1[c];
    }
    out[n0 + tid] = v;
  }
}

// ---------------- launch ----------------

extern "C" void kernel_launch(void* const* d_in, const int* in_sizes, int n_in,
                              void* d_out, int out_size, void* d_ws, size_t ws_size,
                              hipStream_t stream) {
  const float* features = (const float*)d_in[0];
  const int* edges = (const int*)d_in[1];
  // d_in[2] = weights (unused by reference)

  const float *dW1 = (const float*)d_in[3], *db1 = (const float*)d_in[4],
              *dWm1 = (const float*)d_in[5], *dbm1 = (const float*)d_in[6],
              *dWm2 = (const float*)d_in[7], *dbm2 = (const float*)d_in[8],
              *dW2 = (const float*)d_in[9], *db2 = (const float*)d_in[10];
  const float *hW1 = (const float*)d_in[11], *hb1 = (const float*)d_in[12],
              *hWm1 = (const float*)d_in[13], *hbm1 = (const float*)d_in[14],
              *hWm2 = (const float*)d_in[15], *hbm2 = (const float*)d_in[16],
              *hW2 = (const float*)d_in[17], *hb2 = (const float*)d_in[18];
  const float *oW1 = (const float*)d_in[19], *ob1 = (const float*)d_in[20],
              *oWm1 = (const float*)d_in[21], *obm1 = (const float*)d_in[22],
              *oWm2 = (const float*)d_in[23], *obm2 = (const float*)d_in[24],
              *oW2 = (const float*)d_in[25], *ob2 = (const float*)d_in[26];

  // workspace layout (float units)
  float* fws = (float*)d_ws;
  size_t o = 0;
  float* A2 = fws + o;   o += (size_t)N_NODES * RS;   // 5.6M
  float* B2 = fws + o;   o += (size_t)N_NODES * RS;   // 5.6M
  float* gd = fws + o;   o += (size_t)20 * E_EDGES;   // 8.0M  ([c][e])
  float* xrA = fws + o;  o += (size_t)N_NODES * 20;
  float* xrB = fws + o;  o += (size_t)N_NODES * 20;
  int* ip = (int*)(fws + o);
  int* hist = ip;   ip += N_NODES;
  int* off = ip;    ip += N_NODES + 4;
  int* cursor = ip; ip += N_NODES;
  int* srcS = ip;   ip += E_EDGES;
  int* dstS = ip;   ip += E_EDGES;

  const int B256 = 256;
  const int EDGE_G = (E_EDGES + B256 - 1) / B256;  // 1563
  const int NODE8_G = N_NODES / 8;  // 3125, exact

  // build dst-sorted edge list + CSR offsets (recomputed every launch)
  (void)hipMemsetAsync(hist, 0, N_NODES * sizeof(int), stream);
  hist_kernel<<<EDGE_G, B256, 0, stream>>>(edges, hist);
  scan_kernel<<<1, 1024, 0, stream>>>(hist, off, cursor);
  scatter_kernel<<<EDGE_G, B256, 0, stream>>>(edges, cursor, srcS, dstS);

  // layer d: 1 -> 20
  prep_d_kernel<<<NODE8_G, B256, 0, stream>>>(features, dWm1, dbm1, A2, B2, xrA);
  edge_kernel<1><<<EDGE_G, B256, 0, stream>>>(srcS, dstS, A2, B2, dWm2, dbm2, gd);
  afp1_kernel<<<NODE8_G, B256, 0, stream>>>(gd, off, xrA, dW1, db1, dW2, db2,
                                            hWm1, hbm1, A2, B2, xrB);

  // hidden1
  edge_kernel<20><<<EDGE_G, B256, 0, stream>>>(srcS, dstS, A2, B2, hWm2, hbm2, gd);
  afp20_kernel<<<NODE8_G, B256, 0, stream>>>(gd, off, xrB, hW1, hb1, hW2, hb2,
                                             hWm1, hbm1, A2, B2, xrA);
  // hidden2
  edge_kernel<20><<<EDGE_G, B256, 0, stream>>>(srcS, dstS, A2, B2, hWm2, hbm2, gd);
  afp20_kernel<<<NODE8_G, B256, 0, stream>>>(gd, off, xrA, hW1, hb1, hW2, hb2,
                                             hWm1, hbm1, A2, B2, xrB);
  // hidden3 -> preps output layer (oWm1)
  edge_kernel<20><<<EDGE_G, B256, 0, stream>>>(srcS, dstS, A2, B2, hWm2, hbm2, gd);
  afp20_kernel<<<NODE8_G, B256, 0, stream>>>(gd, off, xrB, hW1, hb1, hW2, hb2,
                                             oWm1, obm1, A2, B2, xrA);
  // output layer: 20 -> 1 (no trailing relu)
  edge_kernel<20><<<EDGE_G, B256, 0, stream>>>(srcS, dstS, A2, B2, oWm2, obm2, gd);
  aggfin_out_kernel<<<NODE8_G, B256, 0, stream>>>(gd, off, xrA, oW1, ob1, oW2, ob2,
                                                  (float*)d_out);
}

// Round 11
// 799.152 us; speedup vs baseline: 1.1678x; 1.1678x over previous
//
#include <hip/hip_runtime.h>
#include <hip/hip_fp16.h>

#define N_NODES 25000   // = 3125 * 8 exactly
#define E_EDGES 400000
#define KM 200     // message channels
#define RS 224     // A-row stride (floats): 200 A + 20 x + pad (896 B)
#define RSB 256    // B-row stride (halfs): 200 fp16 B | 20 fp32 x (halfs 200..240) | inv_s (240) (512 B)

// ---------------- sort-by-dst (CSR build) ----------------

__global__ void hist_kernel(const int* __restrict__ edges, int* __restrict__ hist) {
  int e = blockIdx.x * blockDim.x + threadIdx.x;
  if (e < E_EDGES) atomicAdd(&hist[edges[E_EDGES + e]], 1);
}

__global__ void scan_kernel(const int* __restrict__ hist, int* __restrict__ off,
                            int* __restrict__ cursor) {
  __shared__ int sums[1024];
  const int CH = (N_NODES + 1023) / 1024;  // 25
  int tid = threadIdx.x;
  int base = tid * CH;
  int s = 0;
  for (int i = 0; i < CH; i++) {
    int idx = base + i;
    if (idx < N_NODES) s += hist[idx];
  }
  sums[tid] = s;
  __syncthreads();
  for (int d = 1; d < 1024; d <<= 1) {
    int v = (tid >= d) ? sums[tid - d] : 0;
    __syncthreads();
    sums[tid] += v;
    __syncthreads();
  }
  int run = (tid == 0) ? 0 : sums[tid - 1];
  for (int i = 0; i < CH; i++) {
    int idx = base + i;
    if (idx < N_NODES) {
      off[idx] = run;
      cursor[idx] = run;
      run += hist[idx];
    }
  }
  if (tid == 1023) off[N_NODES] = run;  // == E
}

__global__ void scatter_kernel(const int* __restrict__ edges, int* __restrict__ cursor,
                               int* __restrict__ srcS, int* __restrict__ dstS) {
  int e = blockIdx.x * blockDim.x + threadIdx.x;
  if (e < E_EDGES) {
    int s = edges[e];
    int d = edges[E_EDGES + e];
    int pos = atomicAdd(&cursor[d], 1);
    srcS[pos] = s;
    dstS[pos] = d;
  }
}

// ---------------- per-layer kernels ----------------

// prep (layer d, CIN=1): A fp32; B fp16 scaled per node (s_n = 32768/(|x_n|*max|wb|)).
__global__ void __launch_bounds__(256) prep_d_kernel(
    const float* __restrict__ xin,
    const float* __restrict__ Wm1, const float* __restrict__ bm1,
    float* __restrict__ A2, __half* __restrict__ B2h, float* __restrict__ xr) {
  __shared__ unsigned wbmaxu;
  int k = threadIdx.x;  // 0..255
  if (k == 0) wbmaxu = 0;
  __syncthreads();
  float wa = 0.f, wb = 0.f, bm = 0.f;
  if (k < KM) {
    bm = bm1[k];
    wa = Wm1[k];
    wb = Wm1[KM + k];
  }
  float m = (k < KM) ? fabsf(wb) : 0.f;
#pragma unroll
  for (int s = 1; s < 64; s <<= 1) m = fmaxf(m, __shfl_xor(m, s));
  if ((k & 63) == 0) atomicMax(&wbmaxu, __float_as_uint(m));
  __syncthreads();
  float wbmax = fmaxf(__uint_as_float(wbmaxu), 1e-30f);
  int n0 = blockIdx.x * 8;
  for (int i = 0; i < 8; i++) {
    int n = n0 + i;
    float xv = xin[n];
    float denom = fmaxf(fabsf(xv) * wbmax, 1e-30f);
    float sc = 32768.f / denom;
    size_t rowA = (size_t)n * RS;
    __half* rb = B2h + (size_t)n * RSB;
    if (k == 0) {
      xr[n] = xv;
      A2[rowA + KM] = xv;
      *(float*)(rb + 200) = xv;              // x-tail (fp32)
      *(float*)(rb + 240) = denom / 32768.f; // inv_s
    }
    if (k < KM) {
      A2[rowA + k] = bm + xv * wa;
      rb[k] = __float2half(xv * wb * sc);
    }
  }
}

// Edge kernel: one thread per (dst-sorted) edge.
// h_k = relu(A[dst][k] + B16[src][k]*inv_s); gate = h@Wm2 + bm2;
// gd layout [c][e]: coalesced nontemporal dword stores.
template <int CIN>
__global__ void __launch_bounds__(256) edge_kernel(
    const int* __restrict__ srcS, const int* __restrict__ dstS,
    const float* __restrict__ A2, const __half* __restrict__ B2h,
    const float* __restrict__ Wm2, const float* __restrict__ bm2,
    float* __restrict__ gd) {
  int e = blockIdx.x * 256 + threadIdx.x;
  if (e >= E_EDGES) return;
  int src = srcS[e];
  int dst = dstS[e];
  const float* Ar = A2 + (size_t)dst * RS;
  const __half* Br = B2h + (size_t)src * RSB;
  float inv = *(const float*)(Br + 240);
  float gate[CIN];
#pragma unroll
  for (int c = 0; c < CIN; c++) gate[c] = bm2[c];
#pragma unroll 2
  for (int k = 0; k < KM; k += 8) {
    float4 a0 = *(const float4*)(Ar + k);
    float4 a1 = *(const float4*)(Ar + k + 4);
    uint4 braw = *(const uint4*)(Br + k);  // 8 fp16
    float2 f0 = __half22float2(*(const __half2*)&braw.x);
    float2 f1 = __half22float2(*(const __half2*)&braw.y);
    float2 f2 = __half22float2(*(const __half2*)&braw.z);
    float2 f3 = __half22float2(*(const __half2*)&braw.w);
    float h[8];
    h[0] = fmaxf(a0.x + f0.x * inv, 0.f);
    h[1] = fmaxf(a0.y + f0.y * inv, 0.f);
    h[2] = fmaxf(a0.z + f1.x * inv, 0.f);
    h[3] = fmaxf(a0.w + f1.y * inv, 0.f);
    h[4] = fmaxf(a1.x + f2.x * inv, 0.f);
    h[5] = fmaxf(a1.y + f2.y * inv, 0.f);
    h[6] = fmaxf(a1.z + f3.x * inv, 0.f);
    h[7] = fmaxf(a1.w + f3.y * inv, 0.f);
#pragma unroll
    for (int c = 0; c < CIN; c++) {
      float g = gate[c];
#pragma unroll
      for (int j = 0; j < 8; j++) g += h[j] * Wm2[(k + j) * CIN + c];
      gate[c] = g;
    }
  }
  // x-diff tails (fp32 in both rows) + coalesced nontemporal stores
  const float* xta = Ar + KM;
  const float* xtb = (const float*)(Br + 200);
  if constexpr (CIN % 4 == 0) {
#pragma unroll
    for (int q = 0; q < CIN / 4; q++) {
      float4 xa = *(const float4*)(xta + 4 * q);
      float4 xb = *(const float4*)(xtb + 4 * q);
      float xd[4] = {xa.x - xb.x, xa.y - xb.y, xa.z - xb.z, xa.w - xb.w};
#pragma unroll
      for (int j = 0; j < 4; j++) {
        int c = 4 * q + j;
        __builtin_nontemporal_store(gate[c] * xd[j], gd + (size_t)c * E_EDGES + e);
      }
    }
  } else {
#pragma unroll
    for (int c = 0; c < CIN; c++) {
      __builtin_nontemporal_store(gate[c] * (xta[c] - xtb[c]),
                                  gd + (size_t)c * E_EDGES + e);
    }
  }
}

// afp1: after layer-d edge (gd 1-channel). Per block: 8 nodes.
//  phase1 agg; phase2 fin(1->20)+relu -> xv,xrn; phase3 prep (A fp32, B fp16 scaled).
__global__ void __launch_bounds__(256) afp1_kernel(
    const float* __restrict__ gd, const int* __restrict__ off,
    const float* __restrict__ xrp,
    const float* __restrict__ W1, const float* __restrict__ b1,
    const float* __restrict__ W2, const float* __restrict__ b2,
    const float* __restrict__ Wm1n, const float* __restrict__ bm1n,
    float* __restrict__ A2, __half* __restrict__ B2h, float* __restrict__ xrn) {
  __shared__ float ag[8], xp[8], degs[8];
  __shared__ float xv[8][21];
  __shared__ unsigned bmaxu[8];
  int tid = threadIdx.x;
  int n0 = blockIdx.x * 8;
  if (tid < 8) {
    bmaxu[tid] = 0;
    int n = n0 + tid;
    int s = off[n], t = off[n + 1];
    float v = 0.f;
    for (int e = s; e < t; e++) v += gd[e];
    ag[tid] = v;
    xp[tid] = xrp[n];
    degs[tid] = (float)(t - s);
  }
  __syncthreads();
  if (tid < 160) {
    int o = tid >> 3, nl = tid & 7;
    float v = b1[o] + degs[nl] * b2[o] + ag[nl] * W2[o] + xp[nl] * W1[o];
    float r = fmaxf(v, 0.f);
    xv[nl][o] = r;
    xrn[(n0 + nl) * 20 + o] = r;
  }
  __syncthreads();
  int k = tid;
  float aa[8], bb[8];
  if (k < KM) {
    float wa[20], wb[20];
    float bm = bm1n[k];
#pragma unroll
    for (int c = 0; c < 20; c++) {
      wa[c] = Wm1n[c * KM + k];
      wb[c] = Wm1n[(20 + c) * KM + k];
    }
#pragma unroll
    for (int nl = 0; nl < 8; nl++) {
      float a = bm, b = 0.f;
#pragma unroll
      for (int c = 0; c < 20; c++) {
        a += xv[nl][c] * wa[c];
        b += xv[nl][c] * wb[c];
      }
      aa[nl] = a;
      bb[nl] = b;
    }
  }
  float mx[8];
#pragma unroll
  for (int nl = 0; nl < 8; nl++) mx[nl] = (k < KM) ? fabsf(bb[nl]) : 0.f;
#pragma unroll
  for (int s = 1; s < 64; s <<= 1) {
#pragma unroll
    for (int nl = 0; nl < 8; nl++) mx[nl] = fmaxf(mx[nl], __shfl_xor(mx[nl], s));
  }
  if ((tid & 63) == 0) {
#pragma unroll
    for (int nl = 0; nl < 8; nl++) atomicMax(&bmaxu[nl], __float_as_uint(mx[nl]));
  }
  __syncthreads();
  if (k < KM) {
#pragma unroll
    for (int nl = 0; nl < 8; nl++) {
      float bmax = fmaxf(__uint_as_float(bmaxu[nl]), 1e-30f);
      float sc = 32768.f / bmax;
      size_t rowA = (size_t)(n0 + nl) * RS;
      __half* rb = B2h + (size_t)(n0 + nl) * RSB;
      A2[rowA + k] = aa[nl];
      rb[k] = __float2half(bb[nl] * sc);
      if (k == 0) *(float*)(rb + 240) = bmax / 32768.f;
      if (k < 20) {
        A2[rowA + KM + k] = xv[nl][k];
        ((float*)(rb + 200))[k] = xv[nl][k];
      }
    }
  }
}

// afp20: after a hidden edge (gd 20-channel). Same 3 phases, CIN=20.
__global__ void __launch_bounds__(256) afp20_kernel(
    const float* __restrict__ gd, const int* __restrict__ off,
    const float* __restrict__ xrp,
    const float* __restrict__ W1, const float* __restrict__ b1,
    const float* __restrict__ W2, const float* __restrict__ b2,
    const float* __restrict__ Wm1n, const float* __restrict__ bm1n,
    float* __restrict__ A2, __half* __restrict__ B2h, float* __restrict__ xrn) {
  __shared__ float ag[8][21], xp[8][21], xv[8][21], degs[8];
  __shared__ unsigned bmaxu[8];
  int tid = threadIdx.x;
  int n0 = blockIdx.x * 8;
  if (tid < 8) bmaxu[tid] = 0;
  if (tid < 160) {
    int c = tid >> 3, nl = tid & 7;  // adjacent lanes: same c, adjacent n
    int n = n0 + nl;
    int s = off[n], t = off[n + 1];
    const float* g = gd + (size_t)c * E_EDGES;
    float v = 0.f;
    for (int e = s; e < t; e++) v += g[e];
    ag[nl][c] = v;
    xp[nl][c] = xrp[n * 20 + c];
    if (c == 0) degs[nl] = (float)(t - s);
  }
  __syncthreads();
  if (tid < 160) {
    int o = tid >> 3, nl = tid & 7;
    float v = b1[o] + degs[nl] * b2[o];
#pragma unroll
    for (int c = 0; c < 20; c++) {
      v += ag[nl][c] * W2[c * 20 + o] + xp[nl][c] * W1[c * 20 + o];
    }
    float r = fmaxf(v, 0.f);
    xv[nl][o] = r;
    xrn[(n0 + nl) * 20 + o] = r;
  }
  __syncthreads();
  int k = tid;
  float aa[8], bb[8];
  if (k < KM) {
    float wa[20], wb[20];
    float bm = bm1n[k];
#pragma unroll
    for (int c = 0; c < 20; c++) {
      wa[c] = Wm1n[c * KM + k];
      wb[c] = Wm1n[(20 + c) * KM + k];
    }
#pragma unroll
    for (int nl = 0; nl < 8; nl++) {
      float a = bm, b = 0.f;
#pragma unroll
      for (int c = 0; c < 20; c++) {
        a += xv[nl][c] * wa[c];
        b += xv[nl][c] * wb[c];
      }
      aa[nl] = a;
      bb[nl] = b;
    }
  }
  float mx[8];
#pragma unroll
  for (int nl = 0; nl < 8; nl++) mx[nl] = (k < KM) ? fabsf(bb[nl]) : 0.f;
#pragma unroll
  for (int s = 1; s < 64; s <<= 1) {
#pragma unroll
    for (int nl = 0; nl < 8; nl++) mx[nl] = fmaxf(mx[nl], __shfl_xor(mx[nl], s));
  }
  if ((tid & 63) == 0) {
#pragma unroll
    for (int nl = 0; nl < 8; nl++) atomicMax(&bmaxu[nl], __float_as_uint(mx[nl]));
  }
  __syncthreads();
  if (k < KM) {
#pragma unroll
    for (int nl = 0; nl < 8; nl++) {
      float bmax = fmaxf(__uint_as_float(bmaxu[nl]), 1e-30f);
      float sc = 32768.f / bmax;
      size_t rowA = (size_t)(n0 + nl) * RS;
      __half* rb = B2h + (size_t)(n0 + nl) * RSB;
      A2[rowA + k] = aa[nl];
      rb[k] = __float2half(bb[nl] * sc);
      if (k == 0) *(float*)(rb + 240) = bmax / 32768.f;
      if (k < 20) {
        A2[rowA + KM + k] = xv[nl][k];
        ((float*)(rb + 200))[k] = xv[nl][k];
      }
    }
  }
}

// final: agg(20ch) + fin(20->1), no relu, writes d_out.
__global__ void __launch_bounds__(256) aggfin_out_kernel(
    const float* __restrict__ gd, const int* __restrict__ off,
    const float* __restrict__ xrp,
    const float* __restrict__ W1, const float* __restrict__ b1,
    const float* __restrict__ W2, const float* __restrict__ b2,
    float* __restrict__ out) {
  __shared__ float ag[8][21], xp[8][21], degs[8];
  int tid = threadIdx.x;
  int n0 = blockIdx.x * 8;
  if (tid < 160) {
    int c = tid >> 3, nl = tid & 7;
    int n = n0 + nl;
    int s = off[n], t = off[n + 1];
    const float* g = gd + (size_t)c * E_EDGES;
    float v = 0.f;
    for (int e = s; e < t; e++) v += g[e];
    ag[nl][c] = v;
    xp[nl][c] = xrp[n * 20 + c];
    if (c == 0) degs[nl] = (float)(t - s);
  }
  __syncthreads();
  if (tid < 8) {
    float v = b1[0] + degs[tid] * b2[0];
#pragma unroll
    for (int c = 0; c < 20; c++) {
      v += ag[tid][c] * W2[c] + xp[tid][c] * W1[c];
    }
    out[n0 + tid] = v;
  }
}

// ---------------- launch ----------------

extern "C" void kernel_launch(void* const* d_in, const int* in_sizes, int n_in,
                              void* d_out, int out_size, void* d_ws, size_t ws_size,
                              hipStream_t stream) {
  const float* features = (const float*)d_in[0];
  const int* edges = (const int*)d_in[1];
  // d_in[2] = weights (unused by reference)

  const float *dW1 = (const float*)d_in[3], *db1 = (const float*)d_in[4],
              *dWm1 = (const float*)d_in[5], *dbm1 = (const float*)d_in[6],
              *dWm2 = (const float*)d_in[7], *dbm2 = (const float*)d_in[8],
              *dW2 = (const float*)d_in[9], *db2 = (const float*)d_in[10];
  const float *hW1 = (const float*)d_in[11], *hb1 = (const float*)d_in[12],
              *hWm1 = (const float*)d_in[13], *hbm1 = (const float*)d_in[14],
              *hWm2 = (const float*)d_in[15], *hbm2 = (const float*)d_in[16],
              *hW2 = (const float*)d_in[17], *hb2 = (const float*)d_in[18];
  const float *oW1 = (const float*)d_in[19], *ob1 = (const float*)d_in[20],
              *oWm1 = (const float*)d_in[21], *obm1 = (const float*)d_in[22],
              *oWm2 = (const float*)d_in[23], *obm2 = (const float*)d_in[24],
              *oW2 = (const float*)d_in[25], *ob2 = (const float*)d_in[26];

  // workspace layout (float units)
  float* fws = (float*)d_ws;
  size_t o = 0;
  float* A2 = fws + o;    o += (size_t)N_NODES * RS;       // 5.6M
  __half* B2h = (__half*)(fws + o); o += (size_t)N_NODES * RSB / 2;  // 3.2M floats
  float* gd = fws + o;    o += (size_t)20 * E_EDGES;       // 8.0M  ([c][e])
  float* xrA = fws + o;   o += (size_t)N_NODES * 20;
  float* xrB = fws + o;   o += (size_t)N_NODES * 20;
  int* ip = (int*)(fws + o);
  int* hist = ip;   ip += N_NODES;
  int* off = ip;    ip += N_NODES + 4;
  int* cursor = ip; ip += N_NODES;
  int* srcS = ip;   ip += E_EDGES;
  int* dstS = ip;   ip += E_EDGES;

  const int B256 = 256;
  const int EDGE_G = (E_EDGES + B256 - 1) / B256;  // 1563
  const int NODE8_G = N_NODES / 8;  // 3125, exact

  // build dst-sorted edge list + CSR offsets (recomputed every launch)
  (void)hipMemsetAsync(hist, 0, N_NODES * sizeof(int), stream);
  hist_kernel<<<EDGE_G, B256, 0, stream>>>(edges, hist);
  scan_kernel<<<1, 1024, 0, stream>>>(hist, off, cursor);
  scatter_kernel<<<EDGE_G, B256, 0, stream>>>(edges, cursor, srcS, dstS);

  // layer d: 1 -> 20
  prep_d_kernel<<<NODE8_G, B256, 0, stream>>>(features, dWm1, dbm1, A2, B2h, xrA);
  edge_kernel<1><<<EDGE_G, B256, 0, stream>>>(srcS, dstS, A2, B2h, dWm2, dbm2, gd);
  afp1_kernel<<<NODE8_G, B256, 0, stream>>>(gd, off, xrA, dW1, db1, dW2, db2,
                                            hWm1, hbm1, A2, B2h, xrB);

  // hidden1
  edge_kernel<20><<<EDGE_G, B256, 0, stream>>>(srcS, dstS, A2, B2h, hWm2, hbm2, gd);
  afp20_kernel<<<NODE8_G, B256, 0, stream>>>(gd, off, xrB, hW1, hb1, hW2, hb2,
                                             hWm1, hbm1, A2, B2h, xrA);
  // hidden2
  edge_kernel<20><<<EDGE_G, B256, 0, stream>>>(srcS, dstS, A2, B2h, hWm2, hbm2, gd);
  afp20_kernel<<<NODE8_G, B256, 0, stream>>>(gd, off, xrA, hW1, hb1, hW2, hb2,
                                             hWm1, hbm1, A2, B2h, xrB);
  // hidden3 -> preps output layer (oWm1)
  edge_kernel<20><<<EDGE_G, B256, 0, stream>>>(srcS, dstS, A2, B2h, hWm2, hbm2, gd);
  afp20_kernel<<<NODE8_G, B256, 0, stream>>>(gd, off, xrB, hW1, hb1, hW2, hb2,
                                             oWm1, obm1, A2, B2h, xrA);
  // output layer: 20 -> 1 (no trailing relu)
  edge_kernel<20><<<EDGE_G, B256, 0, stream>>>(srcS, dstS, A2, B2h, oWm2, obm2, gd);
  aggfin_out_kernel<<<NODE8_G, B256, 0, stream>>>(gd, off, xrA, oW1, ob1, oW2, ob2,
                                                  (float*)d_out);
}